// Round 3
// baseline (589.212 us; speedup 1.0000x reference)
//
#include <hip/hip_runtime.h>

typedef __attribute__((ext_vector_type(8))) _Float16 half8;
typedef __attribute__((ext_vector_type(4))) float f32x4;

#define NF       1024
#define BM       64
#define NTHREADS 1024     // 16 waves
#define NSLABS   8        // K slabs of 128
#define SLABK    128
#define WCOPY0   2048
#define WCOPYS   2040
#define WTOT     (WCOPY0 + 7 * WCOPYS)   // 16328 fp16 elements

// out[b,i] = mm*x + mm + x,  mm[b,i] = sum_j x[b,j] * w[(j-i) mod 1024]
// MFMA mapping: m->token row, n->output col i, k->j.
// B[k][n] = wext[1024 + k - i], wext[u] = w[u & 1023].
// 8 shifted LDS copies of wext give every lane a 16B-aligned ds_read_b128.
// Circulant shift identity: B(f, k0+32) = B(f-2, k0)  ->  4-deep B register
// rotation, only 2 fresh B ds_reads per 32-k step.
// lds_A line bank = (row mod 8); win*1024B is bank-invariant -> XOR swizzle
// row' = row ^ (win & 7) makes staging writes and all reads conflict-free.
// Epilogue: x re-read from GLOBAL (L2-resident, coalesced 64B/quarter-wave).
// R2 lesson: identity-MFMA transpose epilogue spilled (acc live + idf + xv
// past the 128-reg budget) -> +80MB fetch/+150MB write scratch traffic.
__global__ __launch_bounds__(NTHREADS, 4)
void circ_kernel(const float* __restrict__ x, const float* __restrict__ wsrc,
                 float* __restrict__ out) {
    // A tile: [128 windows of k>>3][64 swizzled rows][8 k-elems], fp16: 128 KiB
    __shared__ __align__(16) _Float16 lds_A[128 * 64 * 8];
    __shared__ __align__(16) _Float16 lds_W[WTOT];            // ~31.9 KiB

    const int tid  = threadIdx.x;
    const int bm   = blockIdx.x;        // 64-row tile index
    const int lane = tid & 63;
    const int wv   = tid >> 6;          // wave 0..15 -> cols [wv*64, +64)
    const int l15  = lane & 15;         // MFMA m (A) / n (B,C) index
    const int quad = lane >> 4;         // MFMA k-block (A,B) / row-block (C)

    // ---- stage 8 shifted copies of circulant weights (fp16) ----
    for (int idx = tid; idx < WTOT; idx += NTHREADS) {
        int s, t;
        if (idx < WCOPY0) { s = 0; t = idx; }
        else { int r = idx - WCOPY0; s = 1 + r / WCOPYS; t = r - (s - 1) * WCOPYS; }
        lds_W[idx] = (_Float16)wsrc[(t + s) & (NF - 1)];
    }

    // ---- A staging: thread -> (row sr, 8-col chunk skc), 8 floats each ----
    const int sr  = tid >> 4;           // 0..63
    const int skc = tid & 15;           // 0..15
    const float* xrow = x + ((size_t)(bm * BM + sr) << 10) + skc * 8;

    f32x4 st0 = *(const f32x4*)(xrow);
    f32x4 st1 = *(const f32x4*)(xrow + 4);

    auto write_slab = [&](int slab) {
        half8 h;
        #pragma unroll
        for (int e = 0; e < 4; ++e) h[e]     = (_Float16)st0[e];
        #pragma unroll
        for (int e = 0; e < 4; ++e) h[4 + e] = (_Float16)st1[e];
        int w = slab * 16 + skc;
        int line = w * 64 + (sr ^ (skc & 7));   // XOR swizzle: w&7 == skc&7
        *(half8*)&lds_A[line * 8] = h;
    };
    write_slab(0);

    // ---- B base offset for logical frag 0; frag f = bbase0 - 16*f + k0 ----
    // (copy selector s = o0 & 7 is invariant in f since 16*f % 8 == 0)
    int bbase0;
    {
        int icol = wv * 64 + l15;               // f = 0 column
        int o0   = 1024 + 8 * quad - icol;
        int s    = o0 & 7;
        int t0   = o0 - s;
        int offs = (s == 0) ? 0 : (WCOPY0 + (s - 1) * WCOPYS);
        bbase0 = offs + t0;
    }

    f32x4 acc[4][4];
    #pragma unroll
    for (int a = 0; a < 4; ++a)
        #pragma unroll
        for (int b = 0; b < 4; ++b)
            acc[a][b] = (f32x4){0.f, 0.f, 0.f, 0.f};

    __syncthreads();

    // ---- initial fill of the B rotation registers (logical f at k0 = 0) ----
    half8 bfr[4];
    #pragma unroll
    for (int f = 0; f < 4; ++f)
        bfr[f] = *(const half8*)&lds_W[bbase0 - 16 * f];

    const int rowb = l15;               // row = mf*16 + l15 (mf added below)

    for (int slab = 0; slab < NSLABS; ++slab) {
        if (slab + 1 < NSLABS) {                 // prefetch next slab -> regs
            const float* xs = xrow + (slab + 1) * SLABK;
            st0 = *(const f32x4*)(xs);
            st1 = *(const f32x4*)(xs + 4);
        }
        #pragma unroll
        for (int ks = 0; ks < 4; ++ks) {
            const int k0   = slab * SLABK + ks * 32;
            const int winq = slab * 16 + ks * 4 + quad;   // (k0>>3)+quad
            const int sw   = (ks * 4 + quad) & 7;         // winq & 7
            half8 afr[4];
            #pragma unroll
            for (int mf = 0; mf < 4; ++mf)
                afr[mf] = *(const half8*)&lds_A[(winq * 64 + ((mf * 16 + rowb) ^ sw)) * 8];
            // logical f order {2,3,0,1}: fresh-loaded frags (0,1) consumed last
            constexpr int ford[4] = {2, 3, 0, 1};
            #pragma unroll
            for (int mf = 0; mf < 4; ++mf)
                #pragma unroll
                for (int ff = 0; ff < 4; ++ff) {
                    const int f = ford[ff];
                    acc[mf][f] = __builtin_amdgcn_mfma_f32_16x16x32_f16(
                        afr[mf], bfr[(f - 2 * ks) & 3], acc[mf][f], 0, 0, 0);
                }
            if (ks < 3) {                        // fresh B frags for next kstep
                const int k0n = k0 + 32;
                bfr[(0 - 2 * (ks + 1)) & 3] = *(const half8*)&lds_W[bbase0 + k0n];
                bfr[(1 - 2 * (ks + 1)) & 3] = *(const half8*)&lds_W[bbase0 - 16 + k0n];
            }
        }
        if (slab + 1 < NSLABS) {
            const int k0n = (slab + 1) * SLABK;  // fresh B frags for next slab
            bfr[0] = *(const half8*)&lds_W[bbase0 + k0n];
            bfr[1] = *(const half8*)&lds_W[bbase0 - 16 + k0n];
            write_slab(slab + 1);                // cvt + ds_write after compute
            __syncthreads();                     // no barrier after last slab:
        }                                        // epilogue doesn't read LDS
    }

    // ---- epilogue: out = mm*x + mm + x ; x re-read from global (L2-hit) ----
    // Per (mf,f,reg): 16 lanes store/load 16 consecutive dwords -> 64B
    // segments, fully coalesced. No LDS, no extra registers, no spills.
    const float* xt = x + ((size_t)(bm * BM) << 10);
    float*       ot = out + ((size_t)(bm * BM) << 10);
    #pragma unroll
    for (int mf = 0; mf < 4; ++mf) {
        #pragma unroll
        for (int f = 0; f < 4; ++f) {
            const int icol = wv * 64 + f * 16 + l15;
            f32x4 mmv = acc[mf][f];
            #pragma unroll
            for (int reg = 0; reg < 4; ++reg) {
                const int m = mf * 16 + quad * 4 + reg;  // C/D row
                float xf = xt[((size_t)m << 10) + icol];
                float mm = mmv[reg];
                ot[((size_t)m << 10) + icol] = mm * xf + mm + xf;
            }
        }
    }
}

extern "C" void kernel_launch(void* const* d_in, const int* in_sizes, int n_in,
                              void* d_out, int out_size, void* d_ws, size_t ws_size,
                              hipStream_t stream) {
    const float* x = (const float*)d_in[0];
    const float* w = (const float*)d_in[1];
    float* o       = (float*)d_out;
    circ_kernel<<<dim3(65536 / BM), dim3(NTHREADS), 0, stream>>>(x, w, o);
}

// Round 4
// 485.445 us; speedup vs baseline: 1.2138x; 1.2138x over previous
//
#include <hip/hip_runtime.h>

typedef __attribute__((ext_vector_type(8))) _Float16 half8;
typedef __attribute__((ext_vector_type(4))) _Float16 half4;
typedef __attribute__((ext_vector_type(4))) float f32x4;

#define NF       1024
#define BM       64
#define NTHREADS 1024     // 16 waves
#define NSLABS   8        // K slabs of 128
#define SLABK    128
#define WCOPY0   2048
#define WCOPYS   2040
#define WTOT     (WCOPY0 + 7 * WCOPYS)   // 16328 fp16 elements

// out[b,i] = mm*x + mm + x,  mm[b,i] = sum_j x[b,j] * w[(j-i) mod 1024]
// SWAPPED-OPERAND MFMA (R4): compute mm^T -> m = output col i, n = token b.
//   A[m=i][k=j] = wext[1024 + j - i]  (circulant, from 8 shifted LDS copies)
//   B[k=j][n=b] = x[b][j]             (token-major LDS tile, chunk-swizzled)
// C/D layout: lane col = token, rows = 4 consecutive i -> epilogue x-read is
// ONE aligned ds_read_b64 (4 consecutive fp16) + one dwordx4 store per
// (mf,f): 32 issue slots vs R1's 128 conflicted scalar slots.
// Circulant rotation now on A: A(mf, k0+32) = A(mf-2, k0) -> 4-deep register
// rotation, 2 fresh A ds_reads per 32-k step.
// x tile swizzle: chunk c of token t stored at position c ^ (t & 7)
// (chunk = 8 fp16 = 16B); kills the 2KB-stride bank aliasing for B-frag
// reads, staging writes, and epilogue reads alike.
// R2/R3 lessons: epilogue x must come from LDS (global re-read misses L2 ->
// +200MB HBM; identity-MFMA transpose spills past the 128-reg budget).
__global__ __launch_bounds__(NTHREADS, 4)
void circ_kernel(const float* __restrict__ x, const float* __restrict__ wsrc,
                 float* __restrict__ out) {
    // x tile: [64 tokens][1024 j] fp16, chunk-swizzled: 128 KiB
    __shared__ __align__(16) _Float16 lds_X[64 * 1024];
    __shared__ __align__(16) _Float16 lds_W[WTOT];            // ~31.9 KiB

    const int tid  = threadIdx.x;
    const int bm   = blockIdx.x;        // 64-token tile index
    const int lane = tid & 63;
    const int wv   = tid >> 6;          // wave 0..15 -> i cols [wv*64, +64)
    const int l15  = lane & 15;         // MFMA m (A) / n (B,C) index
    const int quad = lane >> 4;         // MFMA k-block (A,B) / row-block (C)
    const int xk   = l15 & 7;           // chunk XOR key == (token & 7)

    // ---- stage 8 shifted copies of circulant weights (fp16) ----
    for (int idx = tid; idx < WTOT; idx += NTHREADS) {
        int s, t;
        if (idx < WCOPY0) { s = 0; t = idx; }
        else { int r = idx - WCOPY0; s = 1 + r / WCOPYS; t = r - (s - 1) * WCOPYS; }
        lds_W[idx] = (_Float16)wsrc[(t + s) & (NF - 1)];
    }

    // ---- x staging: thread -> (token sr, 8-col chunk skc), 8 floats ----
    const int sr  = tid >> 4;           // 0..63
    const int skc = tid & 15;           // 0..15
    const float* xrow = x + ((size_t)(bm * BM + sr) << 10) + skc * 8;

    f32x4 st0 = *(const f32x4*)(xrow);
    f32x4 st1 = *(const f32x4*)(xrow + 4);

    auto write_slab = [&](int slab) {
        half8 h;
        #pragma unroll
        for (int e = 0; e < 4; ++e) h[e]     = (_Float16)st0[e];
        #pragma unroll
        for (int e = 0; e < 4; ++e) h[4 + e] = (_Float16)st1[e];
        int w = slab * 16 + skc;                 // chunk index
        int p = w ^ (sr & 7);                    // swizzled position
        *(half8*)&lds_X[sr * 1024 + p * 8] = h;
    };
    write_slab(0);

    // ---- A (circulant) base offset for logical frag mf=0 ----
    // frag mf at k0: abase0 - 16*mf + k0  (16*mf % 8 == 0 -> same copy)
    int abase0;
    {
        int irow = wv * 64 + l15;               // i for mf = 0
        int o0   = 1024 + 8 * quad - irow;
        int s    = o0 & 7;
        int t0   = o0 - s;
        int offs = (s == 0) ? 0 : (WCOPY0 + (s - 1) * WCOPYS);
        abase0 = offs + t0;
    }

    f32x4 acc[4][4];                    // [mf = i-frag][f = token-frag]
    #pragma unroll
    for (int a = 0; a < 4; ++a)
        #pragma unroll
        for (int b = 0; b < 4; ++b)
            acc[a][b] = (f32x4){0.f, 0.f, 0.f, 0.f};

    __syncthreads();

    // ---- initial fill of the A rotation registers (logical mf at k0=0) ----
    half8 afr[4];
    #pragma unroll
    for (int m = 0; m < 4; ++m)
        afr[m] = *(const half8*)&lds_W[abase0 - 16 * m];

    for (int slab = 0; slab < NSLABS; ++slab) {
        if (slab + 1 < NSLABS) {                 // prefetch next slab -> regs
            const float* xs = xrow + (slab + 1) * SLABK;
            st0 = *(const f32x4*)(xs);
            st1 = *(const f32x4*)(xs + 4);
        }
        #pragma unroll
        for (int ks = 0; ks < 4; ++ks) {
            const int k0 = slab * SLABK + ks * 32;
            const int cb = slab * 16 + ks * 4;   // k0 >> 3
            half8 bx[4];                         // B frags: x, 4 token groups
            #pragma unroll
            for (int f = 0; f < 4; ++f)
                bx[f] = *(const half8*)
                    &lds_X[(f * 16 + l15) * 1024 + (((cb + quad) ^ xk)) * 8];
            // logical mf order {2,3,0,1}: fresh A frags (0,1) consumed last
            constexpr int mord[4] = {2, 3, 0, 1};
            #pragma unroll
            for (int mm_ = 0; mm_ < 4; ++mm_) {
                const int mf = mord[mm_];
                #pragma unroll
                for (int f = 0; f < 4; ++f)
                    acc[mf][f] = __builtin_amdgcn_mfma_f32_16x16x32_f16(
                        afr[(mf - 2 * ks) & 3], bx[f], acc[mf][f], 0, 0, 0);
            }
            if (ks < 3) {                        // fresh A frags for next kstep
                const int k0n = k0 + 32;
                afr[(0 - 2 * (ks + 1)) & 3] = *(const half8*)&lds_W[abase0 + k0n];
                afr[(1 - 2 * (ks + 1)) & 3] = *(const half8*)&lds_W[abase0 - 16 + k0n];
            }
        }
        if (slab + 1 < NSLABS) {
            const int k0n = (slab + 1) * SLABK;  // fresh A frags for next slab
            afr[0] = *(const half8*)&lds_W[abase0 + k0n];
            afr[1] = *(const half8*)&lds_W[abase0 - 16 + k0n];
            write_slab(slab + 1);                // cvt + ds_write after compute
            __syncthreads();                     // no barrier after last slab
        }
    }

    // ---- epilogue: out = mm*x + mm + x ----
    // lane holds D rows = 4 consecutive i at col = token: x-read is one
    // aligned b64 (4 fp16) from the resident swizzled tile; store dwordx4.
    #pragma unroll
    for (int mf = 0; mf < 4; ++mf) {
        const int ib = wv * 64 + mf * 16 + quad * 4;  // 4 consecutive i
        const int pc = (ib >> 3) ^ xk;                // swizzled chunk
        const int eo = ib & 7;                        // (quad & 1) * 4
        #pragma unroll
        for (int f = 0; f < 4; ++f) {
            const int tok = f * 16 + l15;
            half4 xv = *(const half4*)&lds_X[tok * 1024 + pc * 8 + eo];
            f32x4 mmv = acc[mf][f];
            f32x4 o;
            #pragma unroll
            for (int reg = 0; reg < 4; ++reg) {
                float xf = (float)xv[reg];
                float mm = mmv[reg];
                o[reg] = mm * xf + mm + xf;
            }
            *(f32x4*)&out[((size_t)(bm * BM + tok) << 10) + ib] = o;
        }
    }
}

extern "C" void kernel_launch(void* const* d_in, const int* in_sizes, int n_in,
                              void* d_out, int out_size, void* d_ws, size_t ws_size,
                              hipStream_t stream) {
    const float* x = (const float*)d_in[0];
    const float* w = (const float*)d_in[1];
    float* o       = (float*)d_out;
    circ_kernel<<<dim3(65536 / BM), dim3(NTHREADS), 0, stream>>>(x, w, o);
}

// Round 5
// 466.607 us; speedup vs baseline: 1.2628x; 1.0404x over previous
//
#include <hip/hip_runtime.h>

typedef __attribute__((ext_vector_type(8))) _Float16 half8;
typedef __attribute__((ext_vector_type(4))) _Float16 half4;
typedef __attribute__((ext_vector_type(4))) float f32x4;

#define NF       1024
#define BM       32       // tokens per block
#define NTHREADS 512      // 8 waves
#define NSLABS   8        // K slabs of 128
#define SLABK    128
#define WCLEN    2048
#define NCOPY    4        // copies shifted by c=0..3; reads via 2x ds_read_b64

// out[b,i] = mm*x + mm + x,  mm[b,i] = sum_j x[b,j] * w[(j-i) mod 1024]
// Swapped-operand MFMA (from R4): m = output col i, n = token b, k = j.
//   A[i][j] = wext[1024 + j - i]  (circulant, 4 shifted LDS copies, b64 reads)
//   B[j][b] = x[b][j]             (token-major LDS tile, chunk-swizzled)
// R5 structural change: 8-wave blocks (BM=32) + 80 KB LDS -> TWO independent
// blocks per CU (16 waves, separate barriers) to break the phase lockstep
// that left every pipe <43% at 1 block/CU (R4: MFMA 33 + VALU 19 + LDS ~38
// summed serially). Wave tile 128i x 32tok: acc[8][2]=64 AGPR (same budget),
// 8-deep circulant sliding window (still 2 fresh A reads per 32-k step),
// bx reused by 8 mf-frags -> 64 FLOP per LDS byte (was 42.7).
// W copies: c = o0 mod 4 keeps reads 8B-aligned -> 2x ds_read_b64; copy
// offsets preserve wext[t0 - 112 + k0] >= 0 since irow <= 911 -> t0 >= 112.
// R2/R3 lessons: epilogue x from LDS only; never exceed 128 regs/wave.
__global__ __launch_bounds__(NTHREADS, 4)
void circ_kernel(const float* __restrict__ x, const float* __restrict__ wsrc,
                 float* __restrict__ out) {
    __shared__ __align__(16) _Float16 lds_X[BM * 1024];      // 64 KiB
    __shared__ __align__(16) _Float16 lds_W[NCOPY * WCLEN];  // 16 KiB -> 80 total

    const int tid  = threadIdx.x;
    const int bm   = blockIdx.x;        // 32-token tile index
    const int lane = tid & 63;
    const int wv   = tid >> 6;          // wave 0..7 -> i in [wv*128, +128)
    const int l15  = lane & 15;         // MFMA m (A) / n (B,C) index
    const int quad = lane >> 4;         // MFMA k-block (A,B) / row-block (C)
    const int xk   = l15 & 7;           // chunk XOR key == (token & 7)

    // ---- stage 4 shifted copies of circulant weights (fp16) ----
    for (int idx = tid; idx < NCOPY * WCLEN; idx += NTHREADS) {
        int c = idx >> 11;               // idx / WCLEN
        int u = idx & (WCLEN - 1);
        lds_W[idx] = (_Float16)wsrc[(u + c) & (NF - 1)];
    }

    // ---- x staging: thread -> (token sr, 8-col chunk skc), 8 floats ----
    const int sr  = tid >> 4;           // 0..31
    const int skc = tid & 15;           // 0..15
    const float* xrow = x + ((size_t)(bm * BM + sr) << 10) + skc * 8;

    f32x4 st0 = *(const f32x4*)(xrow);
    f32x4 st1 = *(const f32x4*)(xrow + 4);

    auto write_slab = [&](int slab) {
        half8 h;
        #pragma unroll
        for (int e = 0; e < 4; ++e) h[e]     = (_Float16)st0[e];
        #pragma unroll
        for (int e = 0; e < 4; ++e) h[4 + e] = (_Float16)st1[e];
        int w = slab * 16 + skc;                 // chunk index
        int p = w ^ (sr & 7);                    // swizzled position
        *(half8*)&lds_X[sr * 1024 + p * 8] = h;
    };
    write_slab(0);

    // ---- A (circulant) base for logical frag mf=0 ----
    // frag mf at k0: abase0 - 16*mf + k0  (all offsets stay 4-elem aligned)
    int abase0;
    {
        int irow = wv * 128 + l15;              // i for mf = 0, <= 911
        int o0   = 1024 + 8 * quad - irow;      // in [113, 1048]
        int c    = o0 & 3;                      // copy selector
        abase0   = c * WCLEN + (o0 - c);        // t0 >= 112 -> t0-112 >= 0
    }

    auto rdW = [&](int off) -> half8 {          // off is 4-elem (8B) aligned
        half4 lo = *(const half4*)&lds_W[off];
        half4 hi = *(const half4*)&lds_W[off + 4];
        return __builtin_shufflevector(lo, hi, 0, 1, 2, 3, 4, 5, 6, 7);
    };

    f32x4 acc[8][2];                    // [mf = i-frag][f = token-frag]
    #pragma unroll
    for (int a = 0; a < 8; ++a) {
        acc[a][0] = (f32x4){0.f, 0.f, 0.f, 0.f};
        acc[a][1] = (f32x4){0.f, 0.f, 0.f, 0.f};
    }

    __syncthreads();

    // ---- initial fill of the 8-deep A sliding window (k0 = 0) ----
    half8 afr[8];
    #pragma unroll
    for (int m = 0; m < 8; ++m)
        afr[m] = rdW(abase0 - 16 * m);

    for (int slab = 0; slab < NSLABS; ++slab) {
        if (slab + 1 < NSLABS) {                 // prefetch next slab -> regs
            const float* xs = xrow + (slab + 1) * SLABK;
            st0 = *(const f32x4*)(xs);
            st1 = *(const f32x4*)(xs + 4);
        }
        #pragma unroll
        for (int ks = 0; ks < 4; ++ks) {
            const int k0 = slab * SLABK + ks * 32;
            const int cb = slab * 16 + ks * 4;   // k0 >> 3
            half8 bx[2];                         // B frags: x, 2 token groups
            #pragma unroll
            for (int f = 0; f < 2; ++f)
                bx[f] = *(const half8*)
                    &lds_X[(f * 16 + l15) * 1024 + ((cb + quad) ^ xk) * 8];
            // mf order {2..7,0,1}: freshly-written slots (0,1) consumed last
            #pragma unroll
            for (int mm_ = 0; mm_ < 8; ++mm_) {
                const int mf = (mm_ + 2) & 7;
                #pragma unroll
                for (int f = 0; f < 2; ++f)
                    acc[mf][f] = __builtin_amdgcn_mfma_f32_16x16x32_f16(
                        afr[(mf - 2 * ks) & 7], bx[f], acc[mf][f], 0, 0, 0);
            }
            if (ks < 3) {                        // fresh A frags for next kstep
                const int k0n = k0 + 32;
                afr[(0 - 2 * (ks + 1)) & 7] = rdW(abase0 + k0n);
                afr[(1 - 2 * (ks + 1)) & 7] = rdW(abase0 - 16 + k0n);
            }
        }
        if (slab + 1 < NSLABS) {
            const int k0n = (slab + 1) * SLABK;  // next slab ks=0 -> slots 0,1
            afr[0] = rdW(abase0 + k0n);
            afr[1] = rdW(abase0 - 16 + k0n);
            write_slab(slab + 1);                // cvt + ds_write after compute
            __syncthreads();                     // no barrier after last slab
        }
    }

    // ---- epilogue: out = mm*x + mm + x ----
    // lane holds D rows = 4 consecutive i at col = token: x-read is one
    // aligned b64 (4 fp16) from the resident swizzled tile; store dwordx4.
    #pragma unroll
    for (int mf = 0; mf < 8; ++mf) {
        const int ib = wv * 128 + mf * 16 + quad * 4;  // 4 consecutive i
        const int pc = (ib >> 3) ^ xk;                 // swizzled chunk
        const int eo = ib & 7;                         // (quad & 1) * 4
        #pragma unroll
        for (int f = 0; f < 2; ++f) {
            const int tok = f * 16 + l15;
            half4 xv = *(const half4*)&lds_X[tok * 1024 + pc * 8 + eo];
            f32x4 mmv = acc[mf][f];
            f32x4 o;
            #pragma unroll
            for (int reg = 0; reg < 4; ++reg) {
                float xf = (float)xv[reg];
                float mm = mmv[reg];
                o[reg] = mm * xf + mm + xf;
            }
            *(f32x4*)&out[((size_t)(bm * BM + tok) << 10) + ib] = o;
        }
    }
}

extern "C" void kernel_launch(void* const* d_in, const int* in_sizes, int n_in,
                              void* d_out, int out_size, void* d_ws, size_t ws_size,
                              hipStream_t stream) {
    const float* x = (const float*)d_in[0];
    const float* w = (const float*)d_in[1];
    float* o       = (float*)d_out;
    circ_kernel<<<dim3(65536 / BM), dim3(NTHREADS), 0, stream>>>(x, w, o);
}